// Round 9
// baseline (457.212 us; speedup 1.0000x reference)
//
#include <hip/hip_runtime.h>
#include <math.h>

typedef __bf16 bf16;
typedef __attribute__((ext_vector_type(8))) __bf16 bf16x8;
typedef __attribute__((ext_vector_type(4))) float f32x4;

// ---------- helpers ----------
__device__ __forceinline__ bf16 f2bf(float f) {
  union { float f; unsigned u; } a; a.f = f;
  unsigned r = a.u + 0x7fffu + ((a.u >> 16) & 1u);   // RNE
  union { unsigned short u; bf16 b; } o; o.u = (unsigned short)(r >> 16);
  return o.b;
}

__device__ __forceinline__ void async_load16(const void* g, void* l) {
  __builtin_amdgcn_global_load_lds(
      (const __attribute__((address_space(1))) void*)g,
      (__attribute__((address_space(3))) void*)l, 16, 0, 0);
}

// ---------- fp32 -> bf16 convert, 4 tensors in one launch ----------
__global__ void f2b4_kernel(const float* __restrict__ a, bf16* __restrict__ oa, int na,
                            const float* __restrict__ b, bf16* __restrict__ ob, int nb,
                            const float* __restrict__ c, bf16* __restrict__ oc, int nc,
                            const float* __restrict__ d, bf16* __restrict__ od, int nd) {
  const int total = na + nb + nc + nd;
  for (int i = blockIdx.x * 256 + threadIdx.x; i < total; i += gridDim.x * 256) {
    const float* s; bf16* o; int j = i;
    if (j < na) { s = a; o = oa; }
    else { j -= na;
      if (j < nb) { s = b; o = ob; }
      else { j -= nb;
        if (j < nc) { s = c; o = oc; }
        else { j -= nc; s = d; o = od; } } }
    o[j] = f2bf(s[j]);
  }
}

// ---------- AdaLN params: silu(x_noise) @ ada_w.T + ada_b -> [2,2304] ----------
__global__ __launch_bounds__(256)
void ada_kernel(const float* __restrict__ xn, const float* __restrict__ aw,
                const float* __restrict__ ab, float* __restrict__ params) {
  const int wid = (blockIdx.x << 2) + (threadIdx.x >> 6);   // 0..4607
  const int ln = threadIdx.x & 63;
  const int j = wid % 2304, b = wid / 2304;
  float s = 0.f;
#pragma unroll
  for (int e = 0; e < 4; e++) {
    int idx = ln + (e << 6);
    float x = xn[b * 256 + idx];
    s += (x / (1.f + __expf(-x))) * aw[j * 256 + idx];
  }
#pragma unroll
  for (int m = 1; m < 64; m <<= 1) s += __shfl_xor(s, m);
  if (ln == 0) params[b * 2304 + j] = s + ab[j];
}

// ---------- LayerNorm (no affine) + modulate -> bf16 ----------
__global__ __launch_bounds__(256)
void ln_mod_kernel(const float* __restrict__ xin, const float* __restrict__ params,
                   int so, int co, bf16* __restrict__ y) {
  const int tok = (blockIdx.x << 2) + (threadIdx.x >> 6);   // one wave per token
  const int ln = threadIdx.x & 63;
  const float* xr = xin + (size_t)tok * 384;
  float v[6]; float s = 0.f, s2 = 0.f;
#pragma unroll
  for (int e = 0; e < 6; e++) { float x = xr[ln + (e << 6)]; v[e] = x; s += x; s2 += x * x; }
#pragma unroll
  for (int m = 1; m < 64; m <<= 1) { s += __shfl_xor(s, m); s2 += __shfl_xor(s2, m); }
  const float mean = s * (1.f / 384.f);
  const float var = s2 * (1.f / 384.f) - mean * mean;
  const float rs = rsqrtf(var + 1e-5f);
  const int b = tok >> 14;
  const float* pr = params + b * 2304;
  bf16* yr = y + (size_t)tok * 384;
#pragma unroll
  for (int e = 0; e < 6; e++) {
    int c = ln + (e << 6);
    float nv = (v[e] - mean) * rs;
    yr[c] = f2bf(nv * (1.f + pr[co + c]) + pr[so + c]);
  }
}

// ---------- GEMM: out[m,n] = A[m,:] . W[n,:]  (A: MxK bf16, W: NxK bf16) ----------
// 256x128 tile, 4 waves (2Mx2N), per-wave 128x64 output (32 MFMA / K-step).
// 3-deep LDS pipeline, counted vmcnt (6 loads/thread/tile, steady vmcnt(12)).
// bn-fastest grid + XCD-chunked bijective swizzle (grid % 8 == 0).
// MODE 0: outb = bf16(acc+bias)
// MODE 1: outb = bf16(gelu_tanh(acc+bias))
// MODE 2: outf = xres + gate[b,n]*(acc+bias)   (fp32)
template<int MODE>
__global__ __launch_bounds__(256)
void gemm_bt(const bf16* __restrict__ A, const bf16* __restrict__ W,
             const float* __restrict__ bias, const float* __restrict__ gate,
             const float* __restrict__ xres, float* __restrict__ outf,
             bf16* __restrict__ outb, int M, int N, int K) {
  __shared__ __align__(16) bf16 As[3][8192];   // 256 x 32
  __shared__ __align__(16) bf16 Bs[3][4096];   // 128 x 32
  const int t = threadIdx.x;
  const int ntn = N >> 7;
  int wg = blockIdx.x;
  wg = (wg & 7) * (gridDim.x >> 3) + (wg >> 3);   // XCD-chunked (grid%8==0)
  const int bm = (wg / ntn) << 8;
  const int bn = (wg % ntn) << 7;
  const int wid = t >> 6, ln = t & 63;
  const int wr = (wid >> 1) << 7;    // 0 / 128
  const int wc = (wid & 1) << 6;     // 0 / 64
  const int lrow = ln & 15;
  // read-side swizzle slot: (ln>>4) ^ f(row), f(r)=(r&3)^((r>>2)&3)
  const int rdoff = (((ln >> 4) ^ (lrow & 3) ^ ((lrow >> 2) & 3)) & 3) << 3;

  f32x4 acc[8][4] = {};

  // staging: thread t owns rows (t>>2)+64p, slot t&3 (LDS dest linear);
  // global source column pre-swizzled with the same involution.
  const int srow = t >> 2;
  const int scol = ((((t & 3) ^ (srow & 3) ^ ((srow >> 2) & 3)) & 3) << 3);
  const bf16* ga = A + (size_t)(bm + srow) * K + scol;
  const bf16* gb = W + (size_t)(bn + srow) * K + scol;
  const size_t rs64 = (size_t)64 * K;
  const int nk = K >> 5;

#define STAGE(buf, kt) do { const int k0_ = (kt) << 5;                 \
    async_load16(ga + k0_,            &As[buf][t * 8]);                \
    async_load16(ga + k0_ + rs64,     &As[buf][2048 + t * 8]);         \
    async_load16(ga + k0_ + 2 * rs64, &As[buf][4096 + t * 8]);         \
    async_load16(ga + k0_ + 3 * rs64, &As[buf][6144 + t * 8]);         \
    async_load16(gb + k0_,            &Bs[buf][t * 8]);                \
    async_load16(gb + k0_ + rs64,     &Bs[buf][2048 + t * 8]); } while (0)

  STAGE(0, 0); STAGE(1, 1); STAGE(2, 2);
  int cur = 0;
  for (int tk = 0; tk < nk; ++tk) {
    // wait for tile tk's 6 loads only (later tiles stay in flight)
    if (tk + 2 < nk)      asm volatile("s_waitcnt vmcnt(12)" ::: "memory");
    else if (tk + 1 < nk) asm volatile("s_waitcnt vmcnt(6)" ::: "memory");
    else                  asm volatile("s_waitcnt vmcnt(0)" ::: "memory");
    asm volatile("s_barrier" ::: "memory");   // buf[cur] complete for all waves

    bf16x8 af[8], bfr[4];
#pragma unroll
    for (int i = 0; i < 8; i++)
      af[i] = *(const bf16x8*)&As[cur][(wr + i * 16 + lrow) * 32 + rdoff];
#pragma unroll
    for (int j = 0; j < 4; j++)
      bfr[j] = *(const bf16x8*)&Bs[cur][(wc + j * 16 + lrow) * 32 + rdoff];
    asm volatile("s_waitcnt lgkmcnt(0)" ::: "memory");
    __builtin_amdgcn_sched_barrier(0);        // rule 18: pin MFMA after lgkmcnt
    asm volatile("s_barrier" ::: "memory");   // all waves done reading buf[cur]

    if (tk + 3 < nk) STAGE(cur, tk + 3);      // refill the buffer just freed

    __builtin_amdgcn_s_setprio(1);
#pragma unroll
    for (int i = 0; i < 8; i++)
#pragma unroll
      for (int j = 0; j < 4; j++)
        acc[i][j] = __builtin_amdgcn_mfma_f32_16x16x32_bf16(af[i], bfr[j], acc[i][j], 0, 0, 0);
    __builtin_amdgcn_s_setprio(0);

    cur = (cur == 2) ? 0 : cur + 1;
  }
#undef STAGE

  const int lr4 = (ln >> 4) << 2;
#pragma unroll
  for (int i = 0; i < 8; i++) {
#pragma unroll
    for (int j = 0; j < 4; j++) {
      const int n = bn + wc + j * 16 + lrow;
      const float bs = bias[n];
#pragma unroll
      for (int r = 0; r < 4; r++) {
        const size_t m = (size_t)(bm + wr + i * 16 + lr4 + r);
        float v = acc[i][j][r] + bs;
        if constexpr (MODE == 0) {
          outb[m * N + n] = f2bf(v);
        } else if constexpr (MODE == 1) {
          float u = 0.7978845608f * (v + 0.044715f * v * v * v);
          float e = __expf(-2.0f * u);
          float th = (1.0f - e) / (1.0f + e);
          v = 0.5f * v * (1.0f + th);
          outb[m * N + n] = f2bf(v);
        } else {
          const float g = gate[(m >> 14) * 2304 + n];
          outf[m * (size_t)N + n] = xres[m * (size_t)N + n] + g * v;
        }
      }
    }
  }
}

// ---------- windowed attention: 1 wave per (window, head) ----------
// qkv: [32768][1152] bf16 (q|k|v each 384). out: [32768][384] bf16.
__global__ __launch_bounds__(256)
void attn_kernel(const bf16* __restrict__ qkv, bf16* __restrict__ out) {
  __shared__ __align__(16) bf16 Pl[4][64][72];
  __shared__ __align__(16) bf16 Vt[4][32][72];
  const int t = threadIdx.x, wv = t >> 6, ln = t & 63;
  const int blk = blockIdx.x;              // 0..1535
  const int win = blk / 3, hg = blk % 3;
  const int head = hg * 4 + wv;
  const int db = win & 3, wb = (win >> 2) & 7, hb = (win >> 5) & 7, b = win >> 8;
  const int base = ((b * 32 + hb * 4) * 32 + wb * 4) * 16 + db * 4;
  const int lrow = ln & 15, lk8 = (ln >> 4) << 3;
  const float scale = 0.17677669529663689f;  // 1/sqrt(32)

#define TOKROW(q) (base + ((q) >> 4) * 512 + (((q) >> 2) & 3) * 16 + ((q) & 3))

  // stage V^T : lane ln owns token ln, reads 32 feats, writes transposed
  {
    size_t rb = (size_t)TOKROW(ln) * 1152 + 768 + head * 32;
#pragma unroll
    for (int fi = 0; fi < 4; fi++) {
      bf16x8 v = *(const bf16x8*)(qkv + rb + fi * 8);
#pragma unroll
      for (int e = 0; e < 8; e++) Vt[wv][fi * 8 + e][ln] = v[e];
    }
  }

  // S = Q K^T (fragments straight from global)
  f32x4 sacc[4][4] = {};
  {
    bf16x8 qf[4], kf[4];
#pragma unroll
    for (int mi = 0; mi < 4; mi++)
      qf[mi] = *(const bf16x8*)(qkv + (size_t)TOKROW(mi * 16 + lrow) * 1152 + head * 32 + lk8);
#pragma unroll
    for (int nj = 0; nj < 4; nj++)
      kf[nj] = *(const bf16x8*)(qkv + (size_t)TOKROW(nj * 16 + lrow) * 1152 + 384 + head * 32 + lk8);
#pragma unroll
    for (int mi = 0; mi < 4; mi++)
#pragma unroll
      for (int nj = 0; nj < 4; nj++)
        sacc[mi][nj] = __builtin_amdgcn_mfma_f32_16x16x32_bf16(qf[mi], kf[nj], sacc[mi][nj], 0, 0, 0);
  }

  // row softmax (rows live on 16-lane groups sharing ln>>4) and write P -> LDS
#pragma unroll
  for (int mi = 0; mi < 4; mi++) {
#pragma unroll
    for (int r = 0; r < 4; r++) {
      float s0 = sacc[mi][0][r] * scale, s1 = sacc[mi][1][r] * scale;
      float s2 = sacc[mi][2][r] * scale, s3 = sacc[mi][3][r] * scale;
      float mx = fmaxf(fmaxf(s0, s1), fmaxf(s2, s3));
#pragma unroll
      for (int m = 1; m < 16; m <<= 1) mx = fmaxf(mx, __shfl_xor(mx, m));
      float e0 = __expf(s0 - mx), e1 = __expf(s1 - mx), e2 = __expf(s2 - mx), e3 = __expf(s3 - mx);
      float sm = e0 + e1 + e2 + e3;
#pragma unroll
      for (int m = 1; m < 16; m <<= 1) sm += __shfl_xor(sm, m);
      const float inv = 1.0f / sm;
      const int row = mi * 16 + ((ln >> 4) << 2) + r;
      Pl[wv][row][0 + lrow]  = f2bf(e0 * inv);
      Pl[wv][row][16 + lrow] = f2bf(e1 * inv);
      Pl[wv][row][32 + lrow] = f2bf(e2 * inv);
      Pl[wv][row][48 + lrow] = f2bf(e3 * inv);
    }
  }

  // O = P V
  f32x4 oacc[4][2] = {};
#pragma unroll
  for (int kk = 0; kk < 2; kk++) {
    bf16x8 pa[4], vb[2];
#pragma unroll
    for (int mi = 0; mi < 4; mi++) pa[mi] = *(const bf16x8*)&Pl[wv][mi * 16 + lrow][kk * 32 + lk8];
#pragma unroll
    for (int nj = 0; nj < 2; nj++) vb[nj] = *(const bf16x8*)&Vt[wv][nj * 16 + lrow][kk * 32 + lk8];
#pragma unroll
    for (int mi = 0; mi < 4; mi++)
#pragma unroll
      for (int nj = 0; nj < 2; nj++)
        oacc[mi][nj] = __builtin_amdgcn_mfma_f32_16x16x32_bf16(pa[mi], vb[nj], oacc[mi][nj], 0, 0, 0);
  }

  // write O
#pragma unroll
  for (int mi = 0; mi < 4; mi++)
#pragma unroll
    for (int nj = 0; nj < 2; nj++)
#pragma unroll
      for (int r = 0; r < 4; r++) {
        int q = mi * 16 + ((ln >> 4) << 2) + r;
        out[(size_t)TOKROW(q) * 384 + head * 32 + nj * 16 + lrow] = f2bf(oacc[mi][nj][r]);
      }
#undef TOKROW
}

// ---------- launcher ----------
extern "C" void kernel_launch(void* const* d_in, const int* in_sizes, int n_in,
                              void* d_out, int out_size, void* d_ws, size_t ws_size,
                              hipStream_t stream) {
  const float* x      = (const float*)d_in[0];
  const float* xnoise = (const float*)d_in[1];
  const float* ada_w  = (const float*)d_in[2];
  const float* ada_b  = (const float*)d_in[3];
  const float* qkv_w  = (const float*)d_in[4];
  const float* qkv_b  = (const float*)d_in[5];
  const float* out_w  = (const float*)d_in[6];
  const float* out_b  = (const float*)d_in[7];
  const float* mlp_w1 = (const float*)d_in[8];
  const float* mlp_b1 = (const float*)d_in[9];
  const float* mlp_w2 = (const float*)d_in[10];
  const float* mlp_b2 = (const float*)d_in[11];
  float* out = (float*)d_out;

  char* ws = (char*)d_ws;
  float* params = (float*)(ws + 0);            // 2*2304 f32
  bf16* wq    = (bf16*)(ws + 18432);           // 1152x384
  bf16* wo    = (bf16*)(ws + 903168);          // 384x384
  bf16* w1    = (bf16*)(ws + 1198080);         // 1536x384
  bf16* w2    = (bf16*)(ws + 2377728);         // 384x1536
  bf16* ybuf  = (bf16*)(ws + 3557376);         // 32768x384  (y1 / attn_out / y2)
  bf16* qkvb  = (bf16*)(ws + 28723200);        // 32768x1152, reused as 32768x1536 h
  bf16* hbuf  = qkvb;

  // weights -> bf16 (one launch)
  f2b4_kernel<<<2048, 256, 0, stream>>>(qkv_w, wq, 442368, out_w, wo, 147456,
                                        mlp_w1, w1, 589824, mlp_w2, w2, 589824);
  // AdaLN params
  ada_kernel<<<1152, 256, 0, stream>>>(xnoise, ada_w, ada_b, params);
  // LN1 + modulate
  ln_mod_kernel<<<8192, 256, 0, stream>>>(x, params, 0, 384, ybuf);
  // qkv  (M-tiles 128, N-tiles 9 -> 1152 blocks)
  gemm_bt<0><<<dim3(128 * 9), 256, 0, stream>>>(ybuf, wq, qkv_b, nullptr, nullptr, nullptr,
                                                qkvb, 32768, 1152, 384);
  // window attention
  attn_kernel<<<1536, 256, 0, stream>>>(qkvb, ybuf);
  // out proj + gate1 + residual -> d_out (fp32)   (128*3 = 384 blocks)
  gemm_bt<2><<<dim3(128 * 3), 256, 0, stream>>>(ybuf, wo, out_b, params + 2 * 384, x, out,
                                                nullptr, 32768, 384, 384);
  // LN2 + modulate
  ln_mod_kernel<<<8192, 256, 0, stream>>>(out, params, 1152, 1536, ybuf);
  // MLP1 + gelu   (128*12 = 1536 blocks)
  gemm_bt<1><<<dim3(128 * 12), 256, 0, stream>>>(ybuf, w1, mlp_b1, nullptr, nullptr, nullptr,
                                                 hbuf, 32768, 1536, 384);
  // MLP2 + gate2 + residual (in-place on d_out)   (128*3 = 384 blocks)
  gemm_bt<2><<<dim3(128 * 3), 256, 0, stream>>>(hbuf, w2, mlp_b2, params + 5 * 384, out, out,
                                                nullptr, 32768, 384, 1536);

  (void)in_sizes; (void)n_in; (void)out_size; (void)ws_size;
}

// Round 10
// 366.994 us; speedup vs baseline: 1.2458x; 1.2458x over previous
//
#include <hip/hip_runtime.h>
#include <math.h>

typedef __bf16 bf16;
typedef __attribute__((ext_vector_type(8))) __bf16 bf16x8;
typedef __attribute__((ext_vector_type(4))) float f32x4;

// ---------- helpers ----------
__device__ __forceinline__ bf16 f2bf(float f) {
  union { float f; unsigned u; } a; a.f = f;
  unsigned r = a.u + 0x7fffu + ((a.u >> 16) & 1u);   // RNE
  union { unsigned short u; bf16 b; } o; o.u = (unsigned short)(r >> 16);
  return o.b;
}

__device__ __forceinline__ void async_load16(const void* g, void* l) {
  __builtin_amdgcn_global_load_lds(
      (const __attribute__((address_space(1))) void*)g,
      (__attribute__((address_space(3))) void*)l, 16, 0, 0);
}

// ---------- weight fp32 -> bf16 fragment-major pack (4 tensors, one launch) ----------
// Fragment (nt, kt) of W[N][K]: lane l holds row nt*16+(l&15), k = kt*32+(l>>4)*8 .. +8.
// Packed elem addr: ((nt*nkt + kt)*64 + l)*8.  One thread per 8-elem chunk.
__global__ __launch_bounds__(256)
void packw4_kernel(const float* __restrict__ s0, bf16* __restrict__ d0, int n0,  // K=384
                   const float* __restrict__ s1, bf16* __restrict__ d1, int n1,  // K=384
                   const float* __restrict__ s2, bf16* __restrict__ d2, int n2,  // K=384
                   const float* __restrict__ s3, bf16* __restrict__ d3, int n3)  // K=1536
{
  int g = blockIdx.x * 256 + threadIdx.x;
  const float* s; bf16* d; int K;
  if (g < n0) { s = s0; d = d0; K = 384; }
  else { g -= n0;
    if (g < n1) { s = s1; d = d1; K = 384; }
    else { g -= n1;
      if (g < n2) { s = s2; d = d2; K = 384; }
      else { g -= n2; s = s3; d = d3; K = 1536; } } }
  const int nkt = K >> 5;
  const int fid = g >> 6, l = g & 63;
  const int nt = fid / nkt, kt = fid - nt * nkt;
  const int row = (nt << 4) + (l & 15);
  const int k = (kt << 5) + ((l >> 4) << 3);
  const float* sp = s + (size_t)row * K + k;
  bf16* dp = d + (size_t)g * 8;
#pragma unroll
  for (int e = 0; e < 8; e++) dp[e] = f2bf(sp[e]);
}

// ---------- AdaLN params: silu(x_noise) @ ada_w.T + ada_b -> [2,2304] ----------
__global__ __launch_bounds__(256)
void ada_kernel(const float* __restrict__ xn, const float* __restrict__ aw,
                const float* __restrict__ ab, float* __restrict__ params) {
  const int wid = (blockIdx.x << 2) + (threadIdx.x >> 6);   // 0..4607
  const int ln = threadIdx.x & 63;
  const int j = wid % 2304, b = wid / 2304;
  float s = 0.f;
#pragma unroll
  for (int e = 0; e < 4; e++) {
    int idx = ln + (e << 6);
    float x = xn[b * 256 + idx];
    s += (x / (1.f + __expf(-x))) * aw[j * 256 + idx];
  }
#pragma unroll
  for (int m = 1; m < 64; m <<= 1) s += __shfl_xor(s, m);
  if (ln == 0) params[b * 2304 + j] = s + ab[j];
}

// ---------- LayerNorm (no affine) + modulate -> bf16 ----------
__global__ __launch_bounds__(256)
void ln_mod_kernel(const float* __restrict__ xin, const float* __restrict__ params,
                   int so, int co, bf16* __restrict__ y) {
  const int tok = (blockIdx.x << 2) + (threadIdx.x >> 6);   // one wave per token
  const int ln = threadIdx.x & 63;
  const float* xr = xin + (size_t)tok * 384;
  float v[6]; float s = 0.f, s2 = 0.f;
#pragma unroll
  for (int e = 0; e < 6; e++) { float x = xr[ln + (e << 6)]; v[e] = x; s += x; s2 += x * x; }
#pragma unroll
  for (int m = 1; m < 64; m <<= 1) { s += __shfl_xor(s, m); s2 += __shfl_xor(s2, m); }
  const float mean = s * (1.f / 384.f);
  const float var = s2 * (1.f / 384.f) - mean * mean;
  const float rs = rsqrtf(var + 1e-5f);
  const int b = tok >> 14;
  const float* pr = params + b * 2304;
  bf16* yr = y + (size_t)tok * 384;
#pragma unroll
  for (int e = 0; e < 6; e++) {
    int c = ln + (e << 6);
    float nv = (v[e] - mean) * rs;
    yr[c] = f2bf(nv * (1.f + pr[co + c]) + pr[so + c]);
  }
}

// ---------- GEMM: out[m,n] = A[m,:] . W[n,:]  (A: MxK bf16; Wp: fragment-packed) ----------
// 128x128 tile, 4 waves (2x2). A: LDS, 3-deep counted-vmcnt pipeline (2 loads/thread/tile).
// B: coalesced register loads from packed global (L2-hot), 2-slot double buffer.
// vm-op order: A0 B0 A1 A2 | iter t: B(t+1), A(t+3) | tails drop stage then loads.
//   TOPW(t) = ops issued after A(t) at iter-t top:  t0:8 t1:8 steady:12 nk-2:10 nk-1:8
//   MFW(t)  = ops after B(t), counted post-issue:   t0:10 t1:8 steady:8 nk-3:6 nk-2:4 nk-1:0
// MODE 0: outb = bf16(acc+bias);  MODE 1: outb = bf16(gelu_tanh(acc+bias));
// MODE 2: outf = xres + gate[b,n]*(acc+bias) (fp32)
template<int MODE>
__global__ __launch_bounds__(256)
void gemm_bt(const bf16* __restrict__ A, const bf16* __restrict__ Wp,
             const float* __restrict__ bias, const float* __restrict__ gate,
             const float* __restrict__ xres, float* __restrict__ outf,
             bf16* __restrict__ outb, int M, int N, int K) {
  __shared__ __align__(16) bf16 As[3][4096];   // 128 x 32 x 3 = 24 KB
  const int t = threadIdx.x;
  const int ntn = N >> 7;
  int wg = blockIdx.x;
  wg = (wg & 7) * (gridDim.x >> 3) + (wg >> 3);   // XCD-chunked (grid%8==0)
  const int bm = (wg / ntn) << 7;
  const int bn = (wg % ntn) << 7;
  const int wid = t >> 6, ln = t & 63;
  const int wr = (wid >> 1) << 6, wc = (wid & 1) << 6;
  const int lrow = ln & 15;
  // A read-side swizzle slot: (ln>>4) ^ f(row), f(r)=(r&3)^((r>>2)&3)
  const int rdoff = (((ln >> 4) ^ (lrow & 3) ^ ((lrow >> 2) & 3)) & 3) << 3;
  const int nk = K >> 5;   // 12 or 48 (nk % 4 == 0, nk >= 8)

  f32x4 acc[4][4] = {};
  bf16x8 bb0[4], bb1[4];   // named B slots (static indexing, rule 20)

  // A staging: thread t owns rows (t>>2), 64+(t>>2); LDS dest linear, global
  // source column pre-swizzled with the same involution.
  const int srow = t >> 2;
  const int scol = ((((t & 3) ^ (srow & 3) ^ ((srow >> 2) & 3)) & 3) << 3);
  const bf16* ga = A + (size_t)(bm + srow) * K + scol;
  const size_t rs64 = (size_t)64 * K;
  // B packed base for this wave: n-tile (bn+wc)/16 + j, lane ln
  const bf16* gw = Wp + ((size_t)(((bn + wc) >> 4) * nk) * 64 + (size_t)ln) * 8;
  const size_t wstride = (size_t)nk * 512;   // elems between n-tiles

#define STAGEA(buf, kt) do { const int k0_ = (kt) << 5;                \
    async_load16(ga + k0_, &As[buf][t * 8]);                           \
    async_load16(ga + k0_ + rs64, &As[buf][2048 + t * 8]); } while (0)
#define LOADB(BBv, kt) do { _Pragma("unroll") for (int j = 0; j < 4; j++) \
    BBv[j] = *(const bf16x8*)(gw + (size_t)j * wstride + (size_t)(kt) * 512); } while (0)

#define BODY(TK, BBC, BBL, TOPW, MFW, DOSTAGE, DOB)                            \
  {                                                                            \
    asm volatile("s_waitcnt vmcnt(" TOPW ")" ::: "memory");                    \
    asm volatile("s_barrier" ::: "memory");       /* As[cur] staged, all waves */ \
    bf16x8 af[4];                                                              \
    _Pragma("unroll") for (int i = 0; i < 4; i++)                              \
      af[i] = *(const bf16x8*)&As[cur][(wr + i * 16 + lrow) * 32 + rdoff];     \
    asm volatile("s_waitcnt lgkmcnt(0)" ::: "memory");                         \
    __builtin_amdgcn_sched_barrier(0);            /* rule 18 */                \
    asm volatile("s_barrier" ::: "memory");       /* reads done: safe to restage */ \
    if (DOB) { LOADB(BBL, (TK) + 1); __builtin_amdgcn_sched_barrier(0); }      \
    if (DOSTAGE) { STAGEA(cur, (TK) + 3); __builtin_amdgcn_sched_barrier(0); } \
    asm volatile("s_waitcnt vmcnt(" MFW ")" ::: "memory");  /* B(TK) ready */  \
    __builtin_amdgcn_sched_barrier(0);                                         \
    __builtin_amdgcn_s_setprio(1);                                             \
    _Pragma("unroll") for (int i = 0; i < 4; i++)                              \
      _Pragma("unroll") for (int j = 0; j < 4; j++)                            \
        acc[i][j] = __builtin_amdgcn_mfma_f32_16x16x32_bf16(af[i], BBC[j], acc[i][j], 0, 0, 0); \
    __builtin_amdgcn_s_setprio(0);                                             \
    cur = (cur == 2) ? 0 : cur + 1;                                            \
  }

  // prologue: A0(2) B0(4) A1(2) A2(2), order pinned
  STAGEA(0, 0);  __builtin_amdgcn_sched_barrier(0);
  LOADB(bb0, 0); __builtin_amdgcn_sched_barrier(0);
  STAGEA(1, 1);  __builtin_amdgcn_sched_barrier(0);
  STAGEA(2, 2);  __builtin_amdgcn_sched_barrier(0);
  int cur = 0;

  BODY(0, bb0, bb1, "8", "10", true, true);
  BODY(1, bb1, bb0, "8", "8",  true, true);
  for (int tk = 2; tk + 5 < nk; tk += 2) {
    BODY(tk,     bb0, bb1, "12", "8", true, true);
    BODY(tk + 1, bb1, bb0, "12", "8", true, true);
  }
  BODY(nk - 4, bb0, bb1, "12", "8", true,  true);
  BODY(nk - 3, bb1, bb0, "12", "6", false, true);
  BODY(nk - 2, bb0, bb1, "10", "4", false, true);
  BODY(nk - 1, bb1, bb0, "8",  "0", false, false);
#undef BODY
#undef LOADB
#undef STAGEA

  const int lr4 = (ln >> 4) << 2;
#pragma unroll
  for (int i = 0; i < 4; i++) {
#pragma unroll
    for (int j = 0; j < 4; j++) {
      const int n = bn + wc + j * 16 + lrow;
      const float bs = bias[n];
#pragma unroll
      for (int r = 0; r < 4; r++) {
        const size_t m = (size_t)(bm + wr + i * 16 + lr4 + r);
        float v = acc[i][j][r] + bs;
        if constexpr (MODE == 0) {
          outb[m * N + n] = f2bf(v);
        } else if constexpr (MODE == 1) {
          float u = 0.7978845608f * (v + 0.044715f * v * v * v);
          float e = __expf(-2.0f * u);
          float th = (1.0f - e) / (1.0f + e);
          v = 0.5f * v * (1.0f + th);
          outb[m * N + n] = f2bf(v);
        } else {
          const float g = gate[(m >> 14) * 2304 + n];
          outf[m * (size_t)N + n] = xres[m * (size_t)N + n] + g * v;
        }
      }
    }
  }
}

// ---------- windowed attention: 1 wave per (window, head) ----------
// qkv: [32768][1152] bf16 (q|k|v each 384). out: [32768][384] bf16.
__global__ __launch_bounds__(256)
void attn_kernel(const bf16* __restrict__ qkv, bf16* __restrict__ out) {
  __shared__ __align__(16) bf16 Pl[4][64][72];
  __shared__ __align__(16) bf16 Vt[4][32][72];
  const int t = threadIdx.x, wv = t >> 6, ln = t & 63;
  const int blk = blockIdx.x;              // 0..1535
  const int win = blk / 3, hg = blk % 3;
  const int head = hg * 4 + wv;
  const int db = win & 3, wb = (win >> 2) & 7, hb = (win >> 5) & 7, b = win >> 8;
  const int base = ((b * 32 + hb * 4) * 32 + wb * 4) * 16 + db * 4;
  const int lrow = ln & 15, lk8 = (ln >> 4) << 3;
  const float scale = 0.17677669529663689f;  // 1/sqrt(32)

#define TOKROW(q) (base + ((q) >> 4) * 512 + (((q) >> 2) & 3) * 16 + ((q) & 3))

  // stage V^T : lane ln owns token ln, reads 32 feats, writes transposed
  {
    size_t rb = (size_t)TOKROW(ln) * 1152 + 768 + head * 32;
#pragma unroll
    for (int fi = 0; fi < 4; fi++) {
      bf16x8 v = *(const bf16x8*)(qkv + rb + fi * 8);
#pragma unroll
      for (int e = 0; e < 8; e++) Vt[wv][fi * 8 + e][ln] = v[e];
    }
  }

  // S = Q K^T (fragments straight from global)
  f32x4 sacc[4][4] = {};
  {
    bf16x8 qf[4], kf[4];
#pragma unroll
    for (int mi = 0; mi < 4; mi++)
      qf[mi] = *(const bf16x8*)(qkv + (size_t)TOKROW(mi * 16 + lrow) * 1152 + head * 32 + lk8);
#pragma unroll
    for (int nj = 0; nj < 4; nj++)
      kf[nj] = *(const bf16x8*)(qkv + (size_t)TOKROW(nj * 16 + lrow) * 1152 + 384 + head * 32 + lk8);
#pragma unroll
    for (int mi = 0; mi < 4; mi++)
#pragma unroll
      for (int nj = 0; nj < 4; nj++)
        sacc[mi][nj] = __builtin_amdgcn_mfma_f32_16x16x32_bf16(qf[mi], kf[nj], sacc[mi][nj], 0, 0, 0);
  }

  // row softmax (rows live on 16-lane groups sharing ln>>4) and write P -> LDS
#pragma unroll
  for (int mi = 0; mi < 4; mi++) {
#pragma unroll
    for (int r = 0; r < 4; r++) {
      float s0 = sacc[mi][0][r] * scale, s1 = sacc[mi][1][r] * scale;
      float s2 = sacc[mi][2][r] * scale, s3 = sacc[mi][3][r] * scale;
      float mx = fmaxf(fmaxf(s0, s1), fmaxf(s2, s3));
#pragma unroll
      for (int m = 1; m < 16; m <<= 1) mx = fmaxf(mx, __shfl_xor(mx, m));
      float e0 = __expf(s0 - mx), e1 = __expf(s1 - mx), e2 = __expf(s2 - mx), e3 = __expf(s3 - mx);
      float sm = e0 + e1 + e2 + e3;
#pragma unroll
      for (int m = 1; m < 16; m <<= 1) sm += __shfl_xor(sm, m);
      const float inv = 1.0f / sm;
      const int row = mi * 16 + ((ln >> 4) << 2) + r;
      Pl[wv][row][0 + lrow]  = f2bf(e0 * inv);
      Pl[wv][row][16 + lrow] = f2bf(e1 * inv);
      Pl[wv][row][32 + lrow] = f2bf(e2 * inv);
      Pl[wv][row][48 + lrow] = f2bf(e3 * inv);
    }
  }

  // O = P V
  f32x4 oacc[4][2] = {};
#pragma unroll
  for (int kk = 0; kk < 2; kk++) {
    bf16x8 pa[4], vb[2];
#pragma unroll
    for (int mi = 0; mi < 4; mi++) pa[mi] = *(const bf16x8*)&Pl[wv][mi * 16 + lrow][kk * 32 + lk8];
#pragma unroll
    for (int nj = 0; nj < 2; nj++) vb[nj] = *(const bf16x8*)&Vt[wv][nj * 16 + lrow][kk * 32 + lk8];
#pragma unroll
    for (int mi = 0; mi < 4; mi++)
#pragma unroll
      for (int nj = 0; nj < 2; nj++)
        oacc[mi][nj] = __builtin_amdgcn_mfma_f32_16x16x32_bf16(pa[mi], vb[nj], oacc[mi][nj], 0, 0, 0);
  }

  // write O
#pragma unroll
  for (int mi = 0; mi < 4; mi++)
#pragma unroll
    for (int nj = 0; nj < 2; nj++)
#pragma unroll
      for (int r = 0; r < 4; r++) {
        int q = mi * 16 + ((ln >> 4) << 2) + r;
        out[(size_t)TOKROW(q) * 384 + head * 32 + nj * 16 + lrow] = f2bf(oacc[mi][nj][r]);
      }
#undef TOKROW
}

// ---------- launcher ----------
extern "C" void kernel_launch(void* const* d_in, const int* in_sizes, int n_in,
                              void* d_out, int out_size, void* d_ws, size_t ws_size,
                              hipStream_t stream) {
  const float* x      = (const float*)d_in[0];
  const float* xnoise = (const float*)d_in[1];
  const float* ada_w  = (const float*)d_in[2];
  const float* ada_b  = (const float*)d_in[3];
  const float* qkv_w  = (const float*)d_in[4];
  const float* qkv_b  = (const float*)d_in[5];
  const float* out_w  = (const float*)d_in[6];
  const float* out_b  = (const float*)d_in[7];
  const float* mlp_w1 = (const float*)d_in[8];
  const float* mlp_b1 = (const float*)d_in[9];
  const float* mlp_w2 = (const float*)d_in[10];
  const float* mlp_b2 = (const float*)d_in[11];
  float* out = (float*)d_out;

  char* ws = (char*)d_ws;
  float* params = (float*)(ws + 0);            // 2*2304 f32
  bf16* wq    = (bf16*)(ws + 18432);           // 1152x384  (frag-packed)
  bf16* wo    = (bf16*)(ws + 903168);          // 384x384   (frag-packed)
  bf16* w1    = (bf16*)(ws + 1198080);         // 1536x384  (frag-packed)
  bf16* w2    = (bf16*)(ws + 2377728);         // 384x1536  (frag-packed)
  bf16* ybuf  = (bf16*)(ws + 3557376);         // 32768x384 (y1 / attn_out / y2)
  bf16* qkvb  = (bf16*)(ws + 28723200);        // 32768x1152, reused as 32768x1536 h
  bf16* hbuf  = qkvb;

  // weights -> bf16 fragment-packed (one launch; 221184 chunks = 864 blocks)
  packw4_kernel<<<864, 256, 0, stream>>>(qkv_w, wq, 55296, out_w, wo, 18432,
                                         mlp_w1, w1, 73728, mlp_w2, w2, 73728);
  // AdaLN params
  ada_kernel<<<1152, 256, 0, stream>>>(xnoise, ada_w, ada_b, params);
  // LN1 + modulate
  ln_mod_kernel<<<8192, 256, 0, stream>>>(x, params, 0, 384, ybuf);
  // qkv  (256 m-tiles x 9 n-tiles)
  gemm_bt<0><<<dim3(256 * 9), 256, 0, stream>>>(ybuf, wq, qkv_b, nullptr, nullptr, nullptr,
                                                qkvb, 32768, 1152, 384);
  // window attention
  attn_kernel<<<1536, 256, 0, stream>>>(qkvb, ybuf);
  // out proj + gate1 + residual -> d_out (fp32)
  gemm_bt<2><<<dim3(256 * 3), 256, 0, stream>>>(ybuf, wo, out_b, params + 2 * 384, x, out,
                                                nullptr, 32768, 384, 384);
  // LN2 + modulate
  ln_mod_kernel<<<8192, 256, 0, stream>>>(out, params, 1152, 1536, ybuf);
  // MLP1 + gelu
  gemm_bt<1><<<dim3(256 * 12), 256, 0, stream>>>(ybuf, w1, mlp_b1, nullptr, nullptr, nullptr,
                                                 hbuf, 32768, 1536, 384);
  // MLP2 + gate2 + residual (in-place on d_out)
  gemm_bt<2><<<dim3(256 * 3), 256, 0, stream>>>(hbuf, w2, mlp_b2, params + 5 * 384, out, out,
                                                nullptr, 32768, 384, 1536);

  (void)in_sizes; (void)n_in; (void)out_size; (void)ws_size;
}